// Round 4
// baseline (626.996 us; speedup 1.0000x reference)
//
#include <hip/hip_runtime.h>
#include <cstdint>
#include <cstddef>

typedef short s16x8 __attribute__((ext_vector_type(8)));
typedef float f32x4 __attribute__((ext_vector_type(4)));

#define NB 1576
#define NT 30
#define ND 1024
#define NH 128
#define LNEPS 1e-5f
#define ATT_SCALE 0.08838834764831845f  // sqrt(1/128)

static __device__ __forceinline__ float bf2f(short s) {
  union { unsigned int u; float f; } c;
  c.u = ((unsigned int)(unsigned short)s) << 16;
  return c.f;
}
static __device__ __forceinline__ short f2bf(float f) {
  union { __bf16 h; short s; } c;
  c.h = (__bf16)f;            // RNE convert
  return c.s;
}
// scalar param load, dtype-adaptive
static __device__ __forceinline__ float ldp(const void* p, int i, int isf32) {
  return isf32 ? ((const float*)p)[i] : bf2f(((const short*)p)[i]);
}
// one MFMA B^T fragment from row-major [K][N] weight at (k0,n0):
// lane gets W[k0 + quad*8 + j][n0 + m_], j=0..7
static __device__ __forceinline__ s16x8 ldfragB(const void* W, int N, int k0, int n0,
                                                int m_, int quad, int isf32) {
  s16x8 r;
  int k = k0 + quad*8, n = n0 + m_;
  if (isf32) {
    const float* p = (const float*)W + (size_t)k*N + n;
#pragma unroll
    for (int j = 0; j < 8; j++) r[j] = f2bf(p[(size_t)j*N]);
  } else {
    const short* p = (const short*)W + (size_t)k*N + n;
#pragma unroll
    for (int j = 0; j < 8; j++) r[j] = p[(size_t)j*N];
  }
  return r;
}

// 32x32 matmul vs a 128x32 weight (K=128): A in LDS [32][136], W direct-global.
static __device__ __forceinline__ void mm32d(const short* Ab, const void* W, const void* bias,
                                             int w, int lane, int isf32,
                                             f32x4 acc[2][2], float bias2[2]) {
  int m_ = lane & 15, quad = lane >> 4;
#pragma unroll
  for (int mt = 0; mt < 2; mt++)
#pragma unroll
    for (int j = 0; j < 2; j++) acc[mt][j] = {0.f, 0.f, 0.f, 0.f};
  bias2[0] = ldp(bias, (2*w)*16 + m_, isf32);
  bias2[1] = ldp(bias, (2*w+1)*16 + m_, isf32);
#pragma unroll
  for (int ks = 0; ks < 4; ks++) {
    s16x8 a[2];
#pragma unroll
    for (int mt = 0; mt < 2; mt++)
      a[mt] = *(const s16x8*)(Ab + (mt*16 + m_)*136 + (ks*4 + quad)*8);
#pragma unroll
    for (int j = 0; j < 2; j++) {
      s16x8 bb = ldfragB(W, NH, ks*32, (2*w + j)*16, m_, quad, isf32);
#pragma unroll
      for (int mt = 0; mt < 2; mt++)
        acc[mt][j] = __builtin_amdgcn_mfma_f32_16x16x32_bf16(a[mt], bb, acc[mt][j], 0, 0, 0);
    }
  }
}

// ---------------- fully fused, zero-workspace: one block per batch ----------------
__global__ __launch_bounds__(256) void fused_all(
    const void* __restrict__ x, const void* __restrict__ W1,
    const void* __restrict__ b1, const void* __restrict__ ln_g, const void* __restrict__ ln_b,
    const void* __restrict__ T_W, const void* __restrict__ T_b,
    const void* __restrict__ Wq, const void* __restrict__ bq,
    const void* __restrict__ Wk, const void* __restrict__ bk,
    const void* __restrict__ Wv, const void* __restrict__ bv,
    const void* __restrict__ Wo, const void* __restrict__ bo,
    const void* __restrict__ n_g, const void* __restrict__ n_b,
    const void* __restrict__ W2, const void* __restrict__ b2,
    void* __restrict__ out) {
  __shared__ __align__(16) short As[32*136];     // x K-slab staging; later av (attn@v)
  __shared__ __align__(16) float hbuf[NT*128];   // h fp32 -> h2 after gating (residual)
  __shared__ float g0s[32];
  __shared__ float sgate[32];
  __shared__ __align__(16) short hn[32*136];     // LN2 out; later h3
  __shared__ __align__(16) short qb[32*136];     // q; later out staging (bf16 path)
  __shared__ __align__(16) short kbf[32*136];    // k
  __shared__ __align__(16) short vt[NH*32];      // v^T [channel][time]
  __shared__ float Sb[32*33];
  __shared__ __align__(16) short Pb[32*32];      // softmax(P) bf16
  // total LDS = 64,896 B  (< 64 KiB)

  int tid = threadIdx.x, lane = tid & 63, w = tid >> 6;
  int m_ = lane & 15, quad = lane >> 4;
  int b = blockIdx.x;

  // ---- dtype sniff on x: bf16 N(0,1) data -> ~64/64 plausible exponents;
  //      fp32 data read as ushort pairs -> ~33/64 (low halves are mantissa garbage)
  int isf32;
  {
    const unsigned short* u = (const unsigned short*)x;
    int pl = 0;
#pragma unroll
    for (int i = 0; i < 64; i++) {
      int e = (u[i] >> 7) & 0xFF;
      pl += (e >= 0x3A && e <= 0x43) ? 1 : 0;
    }
    isf32 = (pl < 48) ? 1 : 0;
  }
  const size_t xbase = (size_t)b * NT * ND;

  // ---- phase 1: C = x @ W1 (32x128, K=1024) ----
  f32x4 acc[2][2];
#pragma unroll
  for (int mt = 0; mt < 2; mt++)
#pragma unroll
    for (int j = 0; j < 2; j++) acc[mt][j] = {0.f, 0.f, 0.f, 0.f};

  for (int kb = 0; kb < 8; kb++) {               // 8 x BK=128
    __syncthreads();
#pragma unroll
    for (int it = 0; it < 2; it++) {             // stage 32 rows x 16 chunks of 8
      int c = it*256 + tid;
      int r = c >> 4, cc = c & 15;
      int rr = r > NT-1 ? NT-1 : r;
      size_t off = xbase + (size_t)rr*ND + kb*128 + cc*8;
      if (!isf32) {
        *(uint4*)(As + r*136 + cc*8) = *(const uint4*)((const short*)x + off);
      } else {
        const float* src = (const float*)x + off;
        float4 f0 = *(const float4*)src, f1 = *(const float4*)(src + 4);
        s16x8 t;
        t[0]=f2bf(f0.x); t[1]=f2bf(f0.y); t[2]=f2bf(f0.z); t[3]=f2bf(f0.w);
        t[4]=f2bf(f1.x); t[5]=f2bf(f1.y); t[6]=f2bf(f1.z); t[7]=f2bf(f1.w);
        *(s16x8*)(As + r*136 + cc*8) = t;
      }
    }
    __syncthreads();
#pragma unroll
    for (int kblk = 0; kblk < 4; kblk++) {
      s16x8 a0 = *(const s16x8*)(As + (m_)*136      + (kblk*4 + quad)*8);
      s16x8 a1 = *(const s16x8*)(As + (16 + m_)*136 + (kblk*4 + quad)*8);
#pragma unroll
      for (int j = 0; j < 2; j++) {
        s16x8 bb = ldfragB(W1, NH, (kb*4 + kblk)*32, (2*w + j)*16, m_, quad, isf32);
        acc[0][j] = __builtin_amdgcn_mfma_f32_16x16x32_bf16(a0, bb, acc[0][j], 0, 0, 0);
        acc[1][j] = __builtin_amdgcn_mfma_f32_16x16x32_bf16(a1, bb, acc[1][j], 0, 0, 0);
      }
    }
  }
  __syncthreads();
  {
    float b1v[2] = {ldp(b1, (2*w)*16 + m_, isf32), ldp(b1, (2*w+1)*16 + m_, isf32)};
#pragma unroll
    for (int mt = 0; mt < 2; mt++)
#pragma unroll
      for (int j = 0; j < 2; j++)
#pragma unroll
        for (int r = 0; r < 4; r++) {
          int row = mt*16 + quad*4 + r;             // C/D: row=quad*4+reg, col=lane&15
          if (row < NT)
            hbuf[row*128 + (2*w + j)*16 + m_] = acc[mt][j][r] + b1v[j];
        }
  }
  __syncthreads();

  // ---- phase 2: h = LN1(C) in place; row means -> g0s ----
  for (int r = w; r < NT; r += 4) {
    float v0 = hbuf[r*128 + lane], v1 = hbuf[r*128 + lane + 64];
    float s = v0 + v1, ss = v0*v0 + v1*v1;
#pragma unroll
    for (int off = 1; off <= 32; off <<= 1) {
      s += __shfl_xor(s, off, 64); ss += __shfl_xor(ss, off, 64);
    }
    float mean = s * (1.f/NH);
    float var = ss * (1.f/NH) - mean*mean;
    float rs = rsqrtf(var + LNEPS);
    float o0 = (v0 - mean) * rs * ldp(ln_g, lane, isf32)      + ldp(ln_b, lane, isf32);
    float o1 = (v1 - mean) * rs * ldp(ln_g, lane + 64, isf32) + ldp(ln_b, lane + 64, isf32);
    hbuf[r*128 + lane] = o0;
    hbuf[r*128 + lane + 64] = o1;
    float rm = o0 + o1;
#pragma unroll
    for (int off = 1; off <= 32; off <<= 1) rm += __shfl_xor(rm, off, 64);
    if (lane == 0) g0s[r] = rm * (1.f/NH);
  }
  __syncthreads();

  // ---- phase 3: gate = softmax(g0 @ T_W + T_b) ----
  if (tid < 32) {
    float y = -1e30f;
    if (tid < NT) {
      y = ldp(T_b, tid, isf32);
      for (int t = 0; t < NT; t++) y += g0s[t] * ldp(T_W, t*NT + tid, isf32);
    }
    float mx = y;
#pragma unroll
    for (int off = 16; off >= 1; off >>= 1) mx = fmaxf(mx, __shfl_xor(mx, off, 64));
    float e = (tid < NT) ? expf(y - mx) : 0.f;
    float s = e;
#pragma unroll
    for (int off = 16; off >= 1; off >>= 1) s += __shfl_xor(s, off, 64);
    if (tid < NT) sgate[tid] = e / s;
  }
  __syncthreads();

  // ---- phase 4: h2 = h * gate ----
#pragma unroll
  for (int it = 0; it < 4; it++) {
    int c = it*256 + tid;
    if (c < 960) {
      int row = c >> 5, i = c & 31;
      float gt = sgate[row];
      float4* p = (float4*)(hbuf + row*128 + i*4);
      float4 v = *p;
      v.x *= gt; v.y *= gt; v.z *= gt; v.w *= gt;
      *p = v;
    }
  }
  __syncthreads();

  // ---- phase 5: hn = LN2(h2) -> bf16; rows 30,31 zero ----
  for (int r = w; r < NT; r += 4) {
    float v0 = hbuf[r*128 + lane], v1 = hbuf[r*128 + lane + 64];
    float s = v0 + v1, ss = v0*v0 + v1*v1;
#pragma unroll
    for (int off = 1; off <= 32; off <<= 1) {
      s += __shfl_xor(s, off, 64); ss += __shfl_xor(ss, off, 64);
    }
    float mean = s * (1.f/NH);
    float var = ss * (1.f/NH) - mean*mean;
    float rs = rsqrtf(var + LNEPS);
    hn[r*136 + lane]      = f2bf((v0 - mean) * rs * ldp(n_g, lane, isf32)      + ldp(n_b, lane, isf32));
    hn[r*136 + lane + 64] = f2bf((v1 - mean) * rs * ldp(n_g, lane + 64, isf32) + ldp(n_b, lane + 64, isf32));
  }
  hn[(30 + (tid >> 7))*136 + (tid & 127)] = 0;
  __syncthreads();

  // ---- phase 6: q, k, v (weights direct from global) ----
  {
    f32x4 a4[2][2];
    float bias2[2];
    mm32d(hn, Wq, bq, w, lane, isf32, a4, bias2);
#pragma unroll
    for (int mt = 0; mt < 2; mt++)
#pragma unroll
      for (int j = 0; j < 2; j++)
#pragma unroll
        for (int r = 0; r < 4; r++)
          qb[(mt*16 + quad*4 + r)*136 + (2*w + j)*16 + m_] = f2bf(a4[mt][j][r] + bias2[j]);
    mm32d(hn, Wk, bk, w, lane, isf32, a4, bias2);
#pragma unroll
    for (int mt = 0; mt < 2; mt++)
#pragma unroll
      for (int j = 0; j < 2; j++)
#pragma unroll
        for (int r = 0; r < 4; r++)
          kbf[(mt*16 + quad*4 + r)*136 + (2*w + j)*16 + m_] = f2bf(a4[mt][j][r] + bias2[j]);
    mm32d(hn, Wv, bv, w, lane, isf32, a4, bias2);
#pragma unroll
    for (int mt = 0; mt < 2; mt++)
#pragma unroll
      for (int j = 0; j < 2; j++)
#pragma unroll
        for (int r = 0; r < 4; r++)
          vt[((2*w + j)*16 + m_)*32 + mt*16 + quad*4 + r] = f2bf(a4[mt][j][r] + bias2[j]); // v^T
  }
  __syncthreads();

  // ---- phase 7: S = q @ k^T (one 16x16 tile per wave) ----
  {
    int mt = w >> 1, nt = w & 1;
    f32x4 sa = {0.f, 0.f, 0.f, 0.f};
#pragma unroll
    for (int ks = 0; ks < 4; ks++) {
      s16x8 a   = *(const s16x8*)(qb  + (mt*16 + m_)*136 + (ks*4 + quad)*8);
      s16x8 bbv = *(const s16x8*)(kbf + (nt*16 + m_)*136 + (ks*4 + quad)*8);
      sa = __builtin_amdgcn_mfma_f32_16x16x32_bf16(a, bbv, sa, 0, 0, 0);
    }
#pragma unroll
    for (int r = 0; r < 4; r++)
      Sb[(mt*16 + quad*4 + r)*33 + nt*16 + m_] = sa[r];
  }
  __syncthreads();

  // ---- phase 8: softmax rows -> P (bf16), pads zeroed ----
  if (tid < NT) {
    float mx = -1e30f;
    for (int jj = 0; jj < NT; jj++) {
      int j = tid + jj; if (j >= NT) j -= NT;
      mx = fmaxf(mx, Sb[tid*33 + j]);
    }
    float sum = 0.f;
    for (int jj = 0; jj < NT; jj++) {
      int j = tid + jj; if (j >= NT) j -= NT;
      float e = expf((Sb[tid*33 + j] - mx) * ATT_SCALE);
      Sb[tid*33 + j] = e; sum += e;
    }
    float rinv = 1.f / sum;
    for (int jj = 0; jj < NT; jj++) {
      int j = tid + jj; if (j >= NT) j -= NT;
      Pb[tid*32 + j] = f2bf(Sb[tid*33 + j] * rinv);
    }
    Pb[tid*32 + 30] = 0;
    Pb[tid*32 + 31] = 0;
  } else if (tid >= 64 && tid < 128) {
    int c = tid - 64;
    Pb[(30 + (c >> 5))*32 + (c & 31)] = 0;
  }
  __syncthreads();

  // ---- phase 9: av = P @ v -> As (reused) ----
  {
    f32x4 a4[2][2];
#pragma unroll
    for (int mt = 0; mt < 2; mt++)
#pragma unroll
      for (int j = 0; j < 2; j++) a4[mt][j] = {0.f, 0.f, 0.f, 0.f};
    s16x8 pa[2];
#pragma unroll
    for (int mt = 0; mt < 2; mt++)
      pa[mt] = *(const s16x8*)(Pb + (mt*16 + m_)*32 + quad*8);
#pragma unroll
    for (int j = 0; j < 2; j++) {
      int nh = (2*w + j)*16 + m_;
      s16x8 vb8 = *(const s16x8*)(vt + nh*32 + quad*8);
#pragma unroll
      for (int mt = 0; mt < 2; mt++)
        a4[mt][j] = __builtin_amdgcn_mfma_f32_16x16x32_bf16(pa[mt], vb8, a4[mt][j], 0, 0, 0);
    }
#pragma unroll
    for (int mt = 0; mt < 2; mt++)
#pragma unroll
      for (int j = 0; j < 2; j++)
#pragma unroll
        for (int r = 0; r < 4; r++)
          As[(mt*16 + quad*4 + r)*136 + (2*w + j)*16 + m_] = f2bf(a4[mt][j][r]);
  }
  __syncthreads();

  // ---- phase 10: h3 = av @ Wo + bo + h2 -> hn; rows 30,31 zero ----
  {
    f32x4 a4[2][2];
    float bias2[2];
    mm32d(As, Wo, bo, w, lane, isf32, a4, bias2);
#pragma unroll
    for (int mt = 0; mt < 2; mt++)
#pragma unroll
      for (int j = 0; j < 2; j++)
#pragma unroll
        for (int r = 0; r < 4; r++) {
          int row = mt*16 + quad*4 + r;
          if (row < NT) {
            int col = (2*w + j)*16 + m_;
            hn[row*136 + col] = f2bf(a4[mt][j][r] + bias2[j] + hbuf[row*128 + col]);
          }
        }
    hn[(30 + (tid >> 7))*136 + (tid & 127)] = 0;
  }
  __syncthreads();

  // ---- phase 11: out = h3 @ W2 + b2, per 128-col group ----
  for (int cg = 0; cg < 8; cg++) {
    f32x4 a2[2][2];
#pragma unroll
    for (int mt = 0; mt < 2; mt++)
#pragma unroll
      for (int j = 0; j < 2; j++) a2[mt][j] = {0.f, 0.f, 0.f, 0.f};
#pragma unroll
    for (int kblk = 0; kblk < 4; kblk++) {
      s16x8 a0 = *(const s16x8*)(hn + (m_)*136      + (kblk*4 + quad)*8);
      s16x8 a1 = *(const s16x8*)(hn + (16 + m_)*136 + (kblk*4 + quad)*8);
#pragma unroll
      for (int j = 0; j < 2; j++) {
        s16x8 bb = ldfragB(W2, ND, kblk*32, cg*128 + (2*w + j)*16, m_, quad, isf32);
        a2[0][j] = __builtin_amdgcn_mfma_f32_16x16x32_bf16(a0, bb, a2[0][j], 0, 0, 0);
        a2[1][j] = __builtin_amdgcn_mfma_f32_16x16x32_bf16(a1, bb, a2[1][j], 0, 0, 0);
      }
    }
    float b2v[2] = {ldp(b2, cg*128 + (2*w)*16 + m_, isf32),
                    ldp(b2, cg*128 + (2*w+1)*16 + m_, isf32)};
    if (!isf32) {                     // stage bf16 rows for coalesced 16B stores
#pragma unroll
      for (int mt = 0; mt < 2; mt++)
#pragma unroll
        for (int j = 0; j < 2; j++)
#pragma unroll
          for (int r = 0; r < 4; r++)
            qb[(mt*16 + quad*4 + r)*136 + (2*w + j)*16 + m_] = f2bf(a2[mt][j][r] + b2v[j]);
    }
    __syncthreads();
    if (!isf32) {
#pragma unroll
      for (int it = 0; it < 2; it++) {
        int c = it*256 + tid;
        if (c < 480) {
          int r = c >> 4, cc = c & 15;
          *(uint4*)((short*)out + ((size_t)b*NT + r)*ND + cg*128 + cc*8) =
              *(const uint4*)(qb + r*136 + cc*8);
        }
      }
    } else {                          // fp32 output: direct scalar stores
#pragma unroll
      for (int mt = 0; mt < 2; mt++)
#pragma unroll
        for (int j = 0; j < 2; j++)
#pragma unroll
          for (int r = 0; r < 4; r++) {
            int row = mt*16 + quad*4 + r;
            if (row < NT)
              ((float*)out)[((size_t)b*NT + row)*ND + cg*128 + (2*w + j)*16 + m_] =
                  a2[mt][j][r] + b2v[j];
          }
    }
    __syncthreads();
  }
}

extern "C" void kernel_launch(void* const* d_in, const int* in_sizes, int n_in,
                              void* d_out, int out_size, void* d_ws, size_t ws_size,
                              hipStream_t stream) {
  // zero-workspace design: d_ws deliberately unused (ws_size unknown/untrusted)
  fused_all<<<NB, 256, 0, stream>>>(
      d_in[0], d_in[1], d_in[2], d_in[3], d_in[4], d_in[5], d_in[6],
      d_in[7], d_in[8], d_in[9], d_in[10], d_in[11], d_in[12], d_in[13],
      d_in[14], d_in[15], d_in[16], d_in[17], d_in[18], d_out);
}